// Round 5
// baseline (671.714 us; speedup 1.0000x reference)
//
#include <hip/hip_runtime.h>
#include <hip/hip_bf16.h>
#include <stdint.h>

#define BATCH 16384
#define MARK  1024
#define NF    40
#define FE    16
#define KDIM  2688      // 2*1024 + 40*16
#define HID   4096
#define BK    64
#define NKT   (KDIM / BK)   // 42 K-tiles, 21 iterations x 2

typedef __bf16 bf16x8 __attribute__((ext_vector_type(8)));
typedef float  f32x4  __attribute__((ext_vector_type(4)));

static __device__ __forceinline__ unsigned short f2bf(float f) {
  union { float f; uint32_t u; } v; v.f = f;
  uint32_t u = v.u;
  uint32_t r = (u + 0x7FFFu + ((u >> 16) & 1u)) >> 16;
  return (unsigned short)r;
}

__global__ __launch_bounds__(256) void build_concat(
    const float* __restrict__ emb_i, const float* __restrict__ emb_a,
    const int* __restrict__ mask, const float* __restrict__ fon,
    const float* __restrict__ foff, unsigned short* __restrict__ out) {
  const int b = blockIdx.x;
  const float4* ri = (const float4*)(emb_i + (size_t)b * MARK);
  const float4* ra = (const float4*)(emb_a + (size_t)b * MARK);
  const int* mrow = mask + b * NF;
  unsigned short* orow = out + (size_t)b * KDIM;
  for (int g = threadIdx.x; g < KDIM / 4; g += 256) {
    const int base = g * 4;
    float4 v;
    if (base < MARK) {
      v = ri[g];
    } else if (base < 2 * MARK) {
      v = ra[g - MARK / 4];
    } else {
      const int idx = base - 2 * MARK;
      const int f = idx >> 4;
      const float* tab = (mrow[f] > 0) ? fon : foff;
      v = *(const float4*)(tab + f * FE + (idx & 15));
    }
    ushort4 o;
    o.x = f2bf(v.x); o.y = f2bf(v.y); o.z = f2bf(v.z); o.w = f2bf(v.w);
    *(ushort4*)(orow + base) = o;
  }
}

__global__ __launch_bounds__(256) void convert_w1(
    const float* __restrict__ w, unsigned short* __restrict__ o, int n4) {
  const int stride = gridDim.x * 256;
  for (int i = blockIdx.x * 256 + threadIdx.x; i < n4; i += stride) {
    float4 v = ((const float4*)w)[i];
    ushort4 u;
    u.x = f2bf(v.x); u.y = f2bf(v.y); u.z = f2bf(v.z); u.w = f2bf(v.w);
    ((ushort4*)o)[i] = u;
  }
}

__global__ __launch_bounds__(256) void out_init(float* __restrict__ out,
                                                const float* __restrict__ b2) {
  const int i = blockIdx.x * 256 + threadIdx.x;
  if (i < BATCH) out[i] = b2[0];
}

#define GL16(g, l)                                                              \
  __builtin_amdgcn_global_load_lds(                                             \
      (const __attribute__((address_space(1))) void*)(g),                       \
      (__attribute__((address_space(3))) void*)(l), 16, 0, 0)

#define BAR()      __builtin_amdgcn_s_barrier()
#define WAIT_VM6() asm volatile("s_waitcnt vmcnt(6)" ::: "memory")
#define WAIT_VM4() asm volatile("s_waitcnt vmcnt(4)" ::: "memory")

// 256x256 tile, BK=64, 8 waves (2M x 4N), 8-phase schedule, 16x16x32 MFMA,
// REGISTER READ-AHEAD: phase P issues phase P+1's ds_reads before P's MFMA
// cluster, so the LDS pipe executes them concurrently with the matrix pipe
// (the compiler's counted lgkmcnt lets them stay outstanding across the MMA).
// vmcnt(4) at P4/P8 TOP gates the loads that read the freshly-landed buffer.
// LDS XOR-swizzle on global source (global_load_lds writes linearly) + reads.
__global__ __launch_bounds__(512, 1) void gemm_fused(
    const unsigned short* __restrict__ A,   // [BATCH, KDIM] bf16
    const unsigned short* __restrict__ Wb,  // [HID, KDIM]  bf16
    const float* __restrict__ b1,
    const float* __restrict__ w2,
    float* __restrict__ out) {
  __shared__ unsigned short sA[2][256 * BK];   // 64 KB
  __shared__ unsigned short sB[2][256 * BK];   // 64 KB
  __shared__ float spart[2][4][128];           // 4 KB cross-wave reduce

  const int tid  = threadIdx.x;
  const int wid  = tid >> 6;
  const int lane = tid & 63;
  const int fr   = lane & 15;   // MFMA fragment row index
  const int k8   = lane >> 4;   // MFMA k-chunk selector (0..3)
  const int wm   = wid >> 2;    // wave M index (0..1)
  const int wn   = wid & 3;     // wave N index (0..3)

  // ---- XCD rectangle swizzle (bijective over 1024 = 8 x 4 x 8 x 4)
  const int bid = blockIdx.x;
  const int xcd = bid & 7;
  const int j   = bid >> 3;
  const int sub = j >> 5;
  const int sm  = (j >> 2) & 7;
  const int sn  = j & 3;
  const int tile_m = (xcd >> 1) * 16 + (sub >> 1) * 8 + sm;   // 0..63
  const int tile_n = (xcd & 1) * 8 + (sub & 1) * 4 + sn;      // 0..15

  // staging: lane l writes LDS row r0+(l>>3), chunk (l&7); source pre-swizzled
  const int lrow = lane >> 3;
  const int lsrc = ((lane & 7) ^ lrow) * 8;   // elements
  const unsigned short* Aptr =
      A + ((size_t)tile_m * 256 + lrow) * KDIM + lsrc;
  const unsigned short* Bptr =
      Wb + ((size_t)tile_n * 256 + lrow) * KDIM + lsrc;

  // read-side swizzled chunk offsets (elements) for kk=0/1
  const int swz0 = ((k8 ^ (fr & 7)) * 8);
  const int swz1 = (((4 + k8) ^ (fr & 7)) * 8);

// A unit MH: rows {g*128 + MH*64 + wid*8}, 2 gloads/wave
#define STAGEA(BUF, MH, KT)                                                    \
  { _Pragma("unroll") for (int g = 0; g < 2; ++g) {                            \
      const int r0 = g * 128 + (MH)*64 + wid * 8;                              \
      GL16(Aptr + (size_t)r0 * KDIM + (size_t)(KT)*BK, &sA[BUF][r0 * BK]); } }

// B unit NH: rows {g*128 + (wid>>2)*64 + NH*32 + (wid&3)*8}
#define STAGEB(BUF, NH, KT)                                                    \
  { _Pragma("unroll") for (int g = 0; g < 2; ++g) {                            \
      const int r0 = g * 128 + (wid >> 2) * 64 + (NH)*32 + (wid & 3) * 8;      \
      GL16(Bptr + (size_t)r0 * KDIM + (size_t)(KT)*BK, &sB[BUF][r0 * BK]); } }

#define LOADA_TO(DST, BUF, MH)                                                 \
  { _Pragma("unroll") for (int i = 0; i < 4; ++i) {                            \
      const unsigned short* p =                                                \
          &sA[BUF][(wm * 128 + (MH)*64 + i * 16 + fr) * BK];                   \
      DST[i][0] = *(const bf16x8*)(p + swz0);                                  \
      DST[i][1] = *(const bf16x8*)(p + swz1); } }

#define LOADB_TO(DST, BUF, NH)                                                 \
  { _Pragma("unroll") for (int jj = 0; jj < 2; ++jj) {                         \
      const unsigned short* p =                                                \
          &sB[BUF][(wn * 64 + (NH)*32 + jj * 16 + fr) * BK];                   \
      DST[jj][0] = *(const bf16x8*)(p + swz0);                                 \
      DST[jj][1] = *(const bf16x8*)(p + swz1); } }

#define MMA_Q(ASET, BSET, MH, NH)                                              \
  { __builtin_amdgcn_s_setprio(1);                                             \
    _Pragma("unroll") for (int i = 0; i < 4; ++i)                              \
    _Pragma("unroll") for (int jj = 0; jj < 2; ++jj) {                         \
      acc[(MH)*4 + i][(NH)*2 + jj] = __builtin_amdgcn_mfma_f32_16x16x32_bf16(  \
          ASET[i][0], BSET[jj][0], acc[(MH)*4 + i][(NH)*2 + jj], 0, 0, 0);     \
      acc[(MH)*4 + i][(NH)*2 + jj] = __builtin_amdgcn_mfma_f32_16x16x32_bf16(  \
          ASET[i][1], BSET[jj][1], acc[(MH)*4 + i][(NH)*2 + jj], 0, 0, 0); }   \
    __builtin_amdgcn_s_setprio(0); }

  f32x4 acc[8][4];
#pragma unroll
  for (int i = 0; i < 8; ++i)
#pragma unroll
    for (int jj = 0; jj < 4; ++jj) acc[i][jj] = (f32x4){0.f, 0.f, 0.f, 0.f};
  bf16x8 aX[4][2], aY[4][2], bX[2][2], bY[2][2];

  // hoist epilogue params (tiny, L2-resident)
  float b1v[4], w2v[4];
  const int gcol = tile_n * 256 + wn * 64 + fr;
#pragma unroll
  for (int jj = 0; jj < 4; ++jj) {
    b1v[jj] = b1[gcol + jj * 16];
    w2v[jj] = w2[gcol + jj * 16];
  }

  // ---- prologue: buf0 all 4 units (8 loads), buf1 {A0,B1,A1} (6 loads)
  STAGEA(0, 0, 0); STAGEB(0, 0, 0); STAGEB(0, 1, 0); STAGEA(0, 1, 0);
  STAGEA(1, 0, 1); STAGEB(1, 1, 1); STAGEA(1, 1, 1);
  WAIT_VM6();   // buf0's 8 landed; buf1's 6 in flight
  BAR();
  LOADA_TO(aX, 0, 0); LOADB_TO(bX, 0, 0);   // prime phase-1 operands

#pragma unroll 1
  for (int t = 0; t < NKT; t += 2) {
    int t2 = t + 2; if (t2 >= NKT) t2 -= NKT;   // wrapped prefetch keeps
    int t3 = t + 3; if (t3 >= NKT) t3 -= NKT;   // vmcnt counts uniform
    // P1: MMA(0,0) even tile; prefetch bY<-b0.nh1; stage b1.B0 @ t+1
    STAGEB(1, 0, t + 1);
    LOADB_TO(bY, 0, 1);
    BAR();
    MMA_Q(aX, bX, 0, 0);
    BAR();
    // P2: MMA(0,1); prefetch aY<-b0.mh1; stage b0.A0 @ t2
    STAGEA(0, 0, t2);
    LOADA_TO(aY, 0, 1);
    BAR();
    MMA_Q(aX, bY, 0, 1);
    BAR();
    // P3: MMA(1,1); prefetch bX<-b0.nh0; stage b0.B1 @ t2
    STAGEB(0, 1, t2);
    LOADB_TO(bX, 0, 0);
    BAR();
    MMA_Q(aY, bY, 1, 1);
    BAR();
    // P4: MMA(1,0); [vm4: buf1 landed] prefetch aX,bY<-buf1; stage b0.A1 @ t2
    WAIT_VM4();
    LOADA_TO(aX, 1, 0); LOADB_TO(bY, 1, 0);
    STAGEA(0, 1, t2);
    BAR();
    MMA_Q(aY, bX, 1, 0);
    BAR();
    // P5: MMA(0,0) odd tile; prefetch bX<-b1.nh1; stage b0.B0 @ t2
    STAGEB(0, 0, t2);
    LOADB_TO(bX, 1, 1);
    BAR();
    MMA_Q(aX, bY, 0, 0);
    BAR();
    // P6: MMA(0,1); prefetch aY<-b1.mh1; stage b1.A0 @ t3
    STAGEA(1, 0, t3);
    LOADA_TO(aY, 1, 1);
    BAR();
    MMA_Q(aX, bX, 0, 1);
    BAR();
    // P7: MMA(1,1); prefetch bY<-b1.nh0; stage b1.B1 @ t3
    STAGEB(1, 1, t3);
    LOADB_TO(bY, 1, 0);
    BAR();
    MMA_Q(aY, bX, 1, 1);
    BAR();
    // P8: MMA(1,0); [vm4: buf0@t2 landed] prefetch aX,bX<-buf0@t2; stage b1.A1 @ t3
    WAIT_VM4();
    LOADA_TO(aX, 0, 0); LOADB_TO(bX, 0, 0);
    STAGEA(1, 1, t3);
    BAR();
    MMA_Q(aY, bY, 1, 0);
    BAR();
  }

  // ---- fused epilogue: out[row] += sum_cols relu(acc + b1[col]) * w2[col]
  // C/D layout: col = fr, row = k8*4 + reg
#pragma unroll
  for (int i = 0; i < 8; ++i) {
    float vs[4];
#pragma unroll
    for (int r = 0; r < 4; ++r) {
      float s = 0.f;
#pragma unroll
      for (int jj = 0; jj < 4; ++jj) {
        float h = acc[i][jj][r] + b1v[jj];
        h = h > 0.f ? h : 0.f;
        s = fmaf(h, w2v[jj], s);
      }
      vs[r] = s;
    }
#pragma unroll
    for (int r = 0; r < 4; ++r) {
      vs[r] += __shfl_xor(vs[r], 1, 16);
      vs[r] += __shfl_xor(vs[r], 2, 16);
      vs[r] += __shfl_xor(vs[r], 4, 16);
      vs[r] += __shfl_xor(vs[r], 8, 16);
    }
    if (fr == 0) {
#pragma unroll
      for (int r = 0; r < 4; ++r)
        spart[wm][wn][i * 16 + k8 * 4 + r] = vs[r];
    }
  }
  __syncthreads();
  if (tid < 256) {
    const int rl = tid & 127, wmr = tid >> 7;
    float s = spart[wmr][0][rl] + spart[wmr][1][rl] +
              spart[wmr][2][rl] + spart[wmr][3][rl];
    atomicAdd(&out[(size_t)tile_m * 256 + tid], s);
  }
}

extern "C" void kernel_launch(void* const* d_in, const int* in_sizes, int n_in,
                              void* d_out, int out_size, void* d_ws, size_t ws_size,
                              hipStream_t stream) {
  const float* emb_i = (const float*)d_in[0];
  const float* emb_a = (const float*)d_in[1];
  const int*   fmask = (const int*)d_in[2];
  const float* fon   = (const float*)d_in[3];
  const float* foff  = (const float*)d_in[4];
  const float* W1    = (const float*)d_in[5];
  const float* b1    = (const float*)d_in[6];
  const float* W2    = (const float*)d_in[7];
  const float* b2    = (const float*)d_in[8];
  float* out = (float*)d_out;

  unsigned short* concat = (unsigned short*)d_ws;                 // BATCH*KDIM bf16
  unsigned short* w1b    = concat + (size_t)BATCH * KDIM;         // HID*KDIM bf16

  build_concat<<<BATCH, 256, 0, stream>>>(emb_i, emb_a, fmask, fon, foff, concat);
  convert_w1<<<2048, 256, 0, stream>>>(W1, w1b, HID * KDIM / 4);
  out_init<<<BATCH / 256, 256, 0, stream>>>(out, b2);
  gemm_fused<<<(BATCH / 256) * (HID / 256), 512, 0, stream>>>(concat, w1b, b1,
                                                              W2, out);
}